// Round 2
// baseline (342.078 us; speedup 1.0000x reference)
//
#include <hip/hip_runtime.h>

// Gaussian blur over ALL axes of (32,3,512,512) f32, sigma = k_size = 5,
// truncate = 4.0 -> radius = 20, 41 taps, 'symmetric' (scipy reflect) edges.
// Separable: pass1 = axis3 (rows), pass2 = axis2 (cols), pass3 = axes 0+1
// fused via folded reflection weight matrices (L=32 and L=3 with r=20 fold
// many times, so each is just a dense LxL matrix along that axis).

#define R     20
#define TAPS  41
#define NB    32
#define CB    3
#define HH    512
#define WW    512
#define PLANE (HH * WW)

__device__ float g_w[TAPS];
__device__ float g_W0[NB * NB];  // folded weights along axis 0 (L=32)
__device__ float g_W1[CB * CB];  // folded weights along axis 1 (L=3)

__device__ __forceinline__ int foldi(int i, int L) {
    // np.pad 'symmetric' index fold: period 2L, mirror second half.
    int p = 2 * L;
    int j = i % p;
    if (j < 0) j += p;
    return (j < L) ? j : (p - 1 - j);
}

__global__ void init_weights(const int* __restrict__ k_size) {
    __shared__ float w[TAPS];
    __shared__ float s_inv;
    int tid = threadIdx.x;  // 64 threads
    float sigma = (float)k_size[0];
    if (tid < TAPS) {
        float x = (float)(tid - R) / sigma;
        w[tid] = expf(-0.5f * x * x);
    }
    __syncthreads();
    if (tid == 0) {
        float s = 0.f;
        for (int t = 0; t < TAPS; ++t) s += w[t];
        s_inv = 1.f / s;
    }
    __syncthreads();
    if (tid < TAPS) {
        w[tid] *= s_inv;
        g_w[tid] = w[tid];
    }
    __syncthreads();
    // Folded matrix along axis0 (L=32): W0[o][i] = sum_t w[t] [fold(o+t-R)==i]
    for (int e = tid; e < NB * NB; e += 64) {
        int o = e >> 5, i = e & 31;
        float s = 0.f;
        for (int t = 0; t < TAPS; ++t)
            if (foldi(o + t - R, NB) == i) s += w[t];
        g_W0[e] = s;
    }
    // Folded matrix along axis1 (L=3)
    for (int e = tid; e < CB * CB; e += 64) {
        int o = e / 3, i = e % 3;
        float s = 0.f;
        for (int t = 0; t < TAPS; ++t)
            if (foldi(o + t - R, CB) == i) s += w[t];
        g_W1[e] = s;
    }
}

// ---- Pass 1: blur along axis 3 (contiguous rows of length 512) ----
// Block = 256 threads = 4 rows x 64 col-groups; each thread -> 8 outputs.
__global__ __launch_bounds__(256) void blur_w_kernel(
        const float* __restrict__ in, float* __restrict__ out) {
    __shared__ float rowp[4][WW + 2 * R];  // padded rows, 552 f32 each
    int tid  = threadIdx.x;
    int lrow = tid >> 6;    // 0..3
    int lc   = tid & 63;    // 0..63
    long long rowIdx = (long long)blockIdx.x * 4 + lrow;  // 0..49151
    const float* src = in + rowIdx * WW;

    for (int i = lc; i < WW + 2 * R; i += 64)
        rowp[lrow][i] = src[foldi(i - R, WW)];
    __syncthreads();

    int o0 = lc * 8;
    float buf[8 + 2 * R];  // 48 consecutive padded values
#pragma unroll
    for (int i = 0; i < 8 + 2 * R; ++i) buf[i] = rowp[lrow][o0 + i];

    float* dst = out + rowIdx * WW + o0;
#pragma unroll
    for (int k = 0; k < 8; ++k) {
        float a = 0.f;
#pragma unroll
        for (int t = 0; t < TAPS; ++t) a = fmaf(g_w[t], buf[k + t], a);
        dst[k] = a;
    }
}

// ---- Pass 2: blur along axis 2 (stride 512) ----
// Block (64,4); tile = 64 cols x 64 output rows; 16 outputs/thread.
__global__ __launch_bounds__(256) void blur_h_kernel(
        const float* __restrict__ in, float* __restrict__ out) {
    __shared__ float tile[64 + 2 * R][64];  // 104 x 64 x 4B = 26.6 KB
    int tx = threadIdx.x;   // 0..63 (column)
    int ty = threadIdx.y;   // 0..3
    int x0 = blockIdx.x * 64;
    int y0 = blockIdx.y * 64;
    long long plane = blockIdx.z;  // 0..95
    const float* src = in + plane * PLANE + x0;

    for (int i = ty; i < 64 + 2 * R; i += 4)
        tile[i][tx] = src[(long long)foldi(y0 - R + i, HH) * WW + tx];
    __syncthreads();

    int yb = ty * 16;
    float buf[16 + 2 * R];  // 56 consecutive column values
#pragma unroll
    for (int i = 0; i < 16 + 2 * R; ++i) buf[i] = tile[yb + i][tx];

    float* dst = out + plane * PLANE + (long long)(y0 + yb) * WW + x0 + tx;
#pragma unroll
    for (int k = 0; k < 16; ++k) {
        float a = 0.f;
#pragma unroll
        for (int t = 0; t < TAPS; ++t) a = fmaf(g_w[t], buf[k + t], a);
        dst[(long long)k * WW] = a;
    }
}

// ---- Pass 3: fused blur along axes 0 (L=32) and 1 (L=3) ----
// One thread per pixel p; computes all 96 (n,c) outputs.
__global__ __launch_bounds__(256) void blur_nc_kernel(
        const float* __restrict__ in, float* __restrict__ out) {
    int p = blockIdx.x * 256 + threadIdx.x;  // 0..262143
    const float* src = in + p;

    float tmp[NB][CB];  // channel-blurred values per n'
#pragma unroll
    for (int n2 = 0; n2 < NB; ++n2) {
        float v0 = src[(n2 * 3 + 0) * PLANE];
        float v1 = src[(n2 * 3 + 1) * PLANE];
        float v2 = src[(n2 * 3 + 2) * PLANE];
        tmp[n2][0] = fmaf(g_W1[0], v0, fmaf(g_W1[1], v1, g_W1[2] * v2));
        tmp[n2][1] = fmaf(g_W1[3], v0, fmaf(g_W1[4], v1, g_W1[5] * v2));
        tmp[n2][2] = fmaf(g_W1[6], v0, fmaf(g_W1[7], v1, g_W1[8] * v2));
    }
    for (int n = 0; n < NB; ++n) {  // rolled: keeps code size sane
        float a0 = 0.f, a1 = 0.f, a2 = 0.f;
#pragma unroll
        for (int n2 = 0; n2 < NB; ++n2) {
            float wv = g_W0[n * NB + n2];
            a0 = fmaf(wv, tmp[n2][0], a0);
            a1 = fmaf(wv, tmp[n2][1], a1);
            a2 = fmaf(wv, tmp[n2][2], a2);
        }
        out[(n * 3 + 0) * PLANE + p] = a0;
        out[(n * 3 + 1) * PLANE + p] = a1;
        out[(n * 3 + 2) * PLANE + p] = a2;
    }
}

extern "C" void kernel_launch(void* const* d_in, const int* in_sizes, int n_in,
                              void* d_out, int out_size, void* d_ws, size_t ws_size,
                              hipStream_t stream) {
    const float* x  = (const float*)d_in[0];
    const int*   ks = (const int*)d_in[1];
    float* out = (float*)d_out;
    float* tmp = (float*)d_ws;  // needs NB*CB*PLANE floats = 100.7 MB

    init_weights<<<1, 64, 0, stream>>>(ks);
    // rows: NB*CB*HH = 49152, 4 rows/block
    blur_w_kernel<<<49152 / 4, 256, 0, stream>>>(x, out);
    blur_h_kernel<<<dim3(WW / 64, HH / 64, NB * CB), dim3(64, 4), 0, stream>>>(out, tmp);
    blur_nc_kernel<<<PLANE / 256, 256, 0, stream>>>(tmp, out);
}